// Round 8
// baseline (161.948 us; speedup 1.0000x reference)
//
#include <hip/hip_runtime.h>
#include <hip/hip_cooperative_groups.h>
#include <math.h>

namespace cg = cooperative_groups;

#define BB 4
#define TQ 256
#define TV 256
#define DD 512
#define UU 128
#define NEGV (-1e9f)

__device__ __forceinline__ float fast_rcp(float x) {
    return __builtin_amdgcn_rcpf(x);   // v_rcp_f32
}

// ==================== fused cooperative kernel ====================
// 512 blocks x 512 thr, 2 blocks/CU co-resident (launch_bounds (512,4)).
// Phase 1: projections -> Eq=exp(2q) (paired), Ek=exp(2k) (transposed)
// Phase 2: scores + masked softmax -> weights
// Phase 3: context = weights @ value (v-split combined in-block via LDS)
__global__ __launch_bounds__(512, 4) void fused_kernel(
    const float* __restrict__ query, const float* __restrict__ value,
    const unsigned char* __restrict__ m,
    const float* __restrict__ W1, const float* __restrict__ W2,
    const float* __restrict__ scale,
    float* __restrict__ ctx, float* __restrict__ weights,
    float* __restrict__ eqp /* [B*TQ/2][U][2] */,
    float* __restrict__ ekT /* [B][U][TV] */) {
    cg::grid_group grid = cg::this_grid();
    __shared__ union SM {
        struct { float xs[4 * DD]; float cmb[3][4][UU]; } p1;          // 14 KB
        struct { float2 eqL[UU]; float sc2[UU]; float pb[2][TV];
                 float redM[2][4]; float redS[2][4]; int fF, fB; } p2; // ~3.6 KB
        struct { float w[4][TV]; float part[4][256]; } p3;             // 8 KB
    } sm;
    int bid = blockIdx.x;
    int tid = threadIdx.x;

    // ---------------- phase 1: projections ----------------
    {
        int which = bid >> 8;              // 0 = q, 1 = k
        int row0 = (bid & 255) * 4;
        const float* X = which ? value : query;
        const float* W = which ? W2 : W1;

        ((float4*)sm.p1.xs)[tid] = ((const float4*)(X + (size_t)row0 * DD))[tid];
        __syncthreads();

        int kc = tid >> 7;                 // K-quarter 0..3
        int u = tid & 127;
        const float* Wp = W + (size_t)(kc * (DD / 4)) * UU + u;
        const float* x0 = sm.p1.xs + kc * (DD / 4);
        float a0 = 0.f, a1 = 0.f, a2 = 0.f, a3 = 0.f;
        #pragma unroll 8
        for (int d = 0; d < DD / 4; ++d) {
            float w = Wp[(size_t)d * UU];          // coalesced across u
            a0 = fmaf(x0[d], w, a0);               // LDS broadcast
            a1 = fmaf(x0[DD + d], w, a1);
            a2 = fmaf(x0[2 * DD + d], w, a2);
            a3 = fmaf(x0[3 * DD + d], w, a3);
        }
        if (kc) {
            sm.p1.cmb[kc - 1][0][u] = a0; sm.p1.cmb[kc - 1][1][u] = a1;
            sm.p1.cmb[kc - 1][2][u] = a2; sm.p1.cmb[kc - 1][3][u] = a3;
        }
        __syncthreads();
        if (!kc) {
            a0 = __expf(2.f * (((a0 + sm.p1.cmb[0][0][u]) + sm.p1.cmb[1][0][u]) + sm.p1.cmb[2][0][u]));
            a1 = __expf(2.f * (((a1 + sm.p1.cmb[0][1][u]) + sm.p1.cmb[1][1][u]) + sm.p1.cmb[2][1][u]));
            a2 = __expf(2.f * (((a2 + sm.p1.cmb[0][2][u]) + sm.p1.cmb[1][2][u]) + sm.p1.cmb[2][2][u]));
            a3 = __expf(2.f * (((a3 + sm.p1.cmb[0][3][u]) + sm.p1.cmb[1][3][u]) + sm.p1.cmb[2][3][u]));
            if (which == 0) {
                int gp = row0 >> 1;
                float2* p = (float2*)eqp;
                p[(size_t)gp * UU + u]       = make_float2(a0, a1);
                p[(size_t)(gp + 1) * UU + u] = make_float2(a2, a3);
            } else {
                int b = row0 >> 8, v0 = row0 & 255;
                float* p = ekT + ((size_t)b * UU + u) * TV + v0;
                p[0] = a0; p[1] = a1; p[2] = a2; p[3] = a3;
            }
        }
    }
    grid.sync();

    // ---------------- phase 2: scores + masked softmax ----------------
    {
        int b = bid >> 7;
        int gp = bid & 127;                // row pair within batch
        int v = tid & 255;
        int h = tid >> 8;                  // u-half

        if (tid == 0) { sm.p2.fF = 0; sm.p2.fB = 0; }
        if (tid < UU) sm.p2.eqL[tid] = ((const float2*)eqp)[(size_t)(b * 128 + gp) * UU + tid];
        else if (tid < 2 * UU) sm.p2.sc2[tid - UU] = -2.f * scale[tid - UU];
        if (tid < 256) {                   // mask layout probe, first 1024 B safe
            uchar4 c4 = ((const uchar4*)m)[tid];
            if (c4.w == 0x3f) sm.p2.fF = 1;               // float32 1.0f tail
            if (c4.y | c4.z | c4.w) sm.p2.fB = 1;         // off-word nonzero -> u8
        }
        __syncthreads();

        const float* kb = ekT + ((size_t)b * UU + h * 64) * TV + v;
        float s0 = 0.f, s1 = 0.f;
        #pragma unroll                      // full unroll: deep load clustering
        for (int i = 0; i < 64; ++i) {
            float ek = kb[(size_t)i * TV];                // coalesced across v
            float2 eq2 = sm.p2.eqL[h * 64 + i];           // LDS broadcast
            float w2 = sm.p2.sc2[h * 64 + i];
            float r0 = fast_rcp(fmaf(eq2.x, ek, 1.f));
            float r1 = fast_rcp(fmaf(eq2.y, ek, 1.f));
            s0 = fmaf(w2, r0, s0);
            s1 = fmaf(w2, r1, s1);
        }
        if (h == 1) { sm.p2.pb[0][v] = s0; sm.p2.pb[1][v] = s1; }
        __syncthreads();

        float mk;
        {
            int idx = b * TV + v;
            bool ok;
            if (sm.p2.fF)      ok = (m[4 * idx + 3] != 0);
            else if (sm.p2.fB) ok = (m[idx] != 0);
            else               ok = (m[4 * idx] != 0);    // int32 LSB
            mk = ok ? __builtin_inff() : NEGV;
        }
        float s[2];
        s[0] = fminf(s0 + sm.p2.pb[0][v], mk);            // h=1 lanes: unused
        s[1] = fminf(s1 + sm.p2.pb[1][v], mk);

        int wid = tid >> 6, lane = tid & 63;
        float e[2];
        #pragma unroll
        for (int r = 0; r < 2; ++r) {
            float mm = s[r];
            #pragma unroll
            for (int off = 32; off >= 1; off >>= 1) mm = fmaxf(mm, __shfl_xor(mm, off));
            if (h == 0 && lane == 0) sm.p2.redM[r][wid] = mm;
        }
        __syncthreads();
        #pragma unroll
        for (int r = 0; r < 2; ++r) {
            float mfull = fmaxf(fmaxf(sm.p2.redM[r][0], sm.p2.redM[r][1]),
                                fmaxf(sm.p2.redM[r][2], sm.p2.redM[r][3]));
            e[r] = __expf(s[r] - mfull);
            float t = e[r];
            #pragma unroll
            for (int off = 32; off >= 1; off >>= 1) t += __shfl_xor(t, off);
            if (h == 0 && lane == 0) sm.p2.redS[r][wid] = t;
        }
        __syncthreads();
        if (h == 0) {
            #pragma unroll
            for (int r = 0; r < 2; ++r) {
                float rs = fast_rcp((sm.p2.redS[r][0] + sm.p2.redS[r][1]) +
                                    (sm.p2.redS[r][2] + sm.p2.redS[r][3]));
                weights[(size_t)(b * TQ + gp * 2 + r) * TV + v] = e[r] * rs;
            }
        }
    }
    grid.sync();

    // ---------------- phase 3: context (v-split combined in-block) ----------------
    {
        int dh = bid & 1;                  // d-half
        int grp = bid >> 1;
        int b = grp >> 6;
        int q0 = (grp & 63) * 4;
        int d = tid & 255;                 // col within half
        int vh = tid >> 8;                 // v-half

        for (int i = tid; i < 4 * TV; i += 512)
            sm.p3.w[i >> 8][i & 255] = weights[(size_t)(b * TQ + q0 + (i >> 8)) * TV + (i & 255)];
        __syncthreads();

        const float* vb = value + ((size_t)b * TV + vh * 128) * DD + dh * 256 + d;
        const float* wr = &sm.p3.w[0][vh * 128];
        float a0 = 0.f, a1 = 0.f, a2 = 0.f, a3 = 0.f;
        #pragma unroll 8
        for (int t = 0; t < 128; ++t) {
            float vv = vb[(size_t)t * DD];                // coalesced across d
            a0 = fmaf(wr[0 * TV + t], vv, a0);
            a1 = fmaf(wr[1 * TV + t], vv, a1);
            a2 = fmaf(wr[2 * TV + t], vv, a2);
            a3 = fmaf(wr[3 * TV + t], vv, a3);
        }
        if (vh == 1) {
            sm.p3.part[0][d] = a0; sm.p3.part[1][d] = a1;
            sm.p3.part[2][d] = a2; sm.p3.part[3][d] = a3;
        }
        __syncthreads();
        if (vh == 0) {
            float* out = ctx + (size_t)(b * TQ + q0) * DD + dh * 256 + d;
            out[0 * DD] = a0 + sm.p3.part[0][d];
            out[1 * DD] = a1 + sm.p3.part[1][d];
            out[2 * DD] = a2 + sm.p3.part[2][d];
            out[3 * DD] = a3 + sm.p3.part[3][d];
        }
    }
}

// ==================== fallback path (proven 33.2 us, 4 kernels) ====================
__global__ __launch_bounds__(512, 4) void proj_kernel(
    const float* __restrict__ query, const float* __restrict__ value,
    const float* __restrict__ W1, const float* __restrict__ W2,
    float* __restrict__ eqp, float* __restrict__ ekT) {
    int bid = blockIdx.x;
    int which = bid >> 8;
    int row0 = (bid & 255) * 4;
    const float* X = which ? value : query;
    const float* W = which ? W2 : W1;
    __shared__ float xs[4 * DD];
    __shared__ float cmb[3][4][UU];
    int tid = threadIdx.x;
    ((float4*)xs)[tid] = ((const float4*)(X + (size_t)row0 * DD))[tid];
    __syncthreads();
    int kc = tid >> 7;
    int u = tid & 127;
    const float* Wp = W + (size_t)(kc * (DD / 4)) * UU + u;
    const float* x0 = xs + kc * (DD / 4);
    float a0 = 0.f, a1 = 0.f, a2 = 0.f, a3 = 0.f;
    #pragma unroll 8
    for (int d = 0; d < DD / 4; ++d) {
        float w = Wp[(size_t)d * UU];
        a0 = fmaf(x0[d], w, a0);
        a1 = fmaf(x0[DD + d], w, a1);
        a2 = fmaf(x0[2 * DD + d], w, a2);
        a3 = fmaf(x0[3 * DD + d], w, a3);
    }
    if (kc) {
        cmb[kc - 1][0][u] = a0; cmb[kc - 1][1][u] = a1;
        cmb[kc - 1][2][u] = a2; cmb[kc - 1][3][u] = a3;
    }
    __syncthreads();
    if (!kc) {
        a0 = __expf(2.f * (((a0 + cmb[0][0][u]) + cmb[1][0][u]) + cmb[2][0][u]));
        a1 = __expf(2.f * (((a1 + cmb[0][1][u]) + cmb[1][1][u]) + cmb[2][1][u]));
        a2 = __expf(2.f * (((a2 + cmb[0][2][u]) + cmb[1][2][u]) + cmb[2][2][u]));
        a3 = __expf(2.f * (((a3 + cmb[0][3][u]) + cmb[1][3][u]) + cmb[2][3][u]));
        if (which == 0) {
            int gp = row0 >> 1;
            float2* p = (float2*)eqp;
            p[(size_t)gp * UU + u]       = make_float2(a0, a1);
            p[(size_t)(gp + 1) * UU + u] = make_float2(a2, a3);
        } else {
            int b = row0 >> 8, v0 = row0 & 255;
            float* p = ekT + ((size_t)b * UU + u) * TV + v0;
            p[0] = a0; p[1] = a1; p[2] = a2; p[3] = a3;
        }
    }
}

__global__ __launch_bounds__(512, 4) void scores_kernel(
    const float* __restrict__ eqp, const float* __restrict__ ekT,
    const float* __restrict__ scale, const unsigned char* __restrict__ m,
    float* __restrict__ weights) {
    int blk = blockIdx.x;
    int b = blk >> 7;
    int gp = blk & 127;
    int tid = threadIdx.x;
    int v = tid & 255;
    int h = tid >> 8;
    __shared__ float2 eqL[UU];
    __shared__ float sc2[UU];
    __shared__ float pb[2][TV];
    __shared__ int flagF, flagB;
    __shared__ float redM[2][4], redS[2][4];
    if (tid == 0) { flagF = 0; flagB = 0; }
    if (tid < UU) eqL[tid] = ((const float2*)eqp)[(size_t)(b * 128 + gp) * UU + tid];
    else if (tid < 2 * UU) sc2[tid - UU] = -2.f * scale[tid - UU];
    if (tid < 256) {
        uchar4 c4 = ((const uchar4*)m)[tid];
        if (c4.w == 0x3f) flagF = 1;
        if (c4.y | c4.z | c4.w) flagB = 1;
    }
    __syncthreads();
    const float* kb = ekT + ((size_t)b * UU + h * 64) * TV + v;
    float s0 = 0.f, s1 = 0.f;
    #pragma unroll
    for (int i = 0; i < 64; ++i) {
        float ek = kb[(size_t)i * TV];
        float2 eq2 = eqL[h * 64 + i];
        float w2 = sc2[h * 64 + i];
        float r0 = fast_rcp(fmaf(eq2.x, ek, 1.f));
        float r1 = fast_rcp(fmaf(eq2.y, ek, 1.f));
        s0 = fmaf(w2, r0, s0);
        s1 = fmaf(w2, r1, s1);
    }
    if (h == 1) { pb[0][v] = s0; pb[1][v] = s1; }
    __syncthreads();
    float mk;
    {
        int idx = b * TV + v;
        bool ok;
        if (flagF)      ok = (m[4 * idx + 3] != 0);
        else if (flagB) ok = (m[idx] != 0);
        else            ok = (m[4 * idx] != 0);
        mk = ok ? __builtin_inff() : NEGV;
    }
    float s[2];
    s[0] = fminf(s0 + pb[0][v], mk);
    s[1] = fminf(s1 + pb[1][v], mk);
    int wid = tid >> 6, lane = tid & 63;
    float e[2];
    #pragma unroll
    for (int r = 0; r < 2; ++r) {
        float mm = s[r];
        #pragma unroll
        for (int off = 32; off >= 1; off >>= 1) mm = fmaxf(mm, __shfl_xor(mm, off));
        if (h == 0 && lane == 0) redM[r][wid] = mm;
    }
    __syncthreads();
    #pragma unroll
    for (int r = 0; r < 2; ++r) {
        float mfull = fmaxf(fmaxf(redM[r][0], redM[r][1]),
                            fmaxf(redM[r][2], redM[r][3]));
        e[r] = __expf(s[r] - mfull);
        float t = e[r];
        #pragma unroll
        for (int off = 32; off >= 1; off >>= 1) t += __shfl_xor(t, off);
        if (h == 0 && lane == 0) redS[r][wid] = t;
    }
    __syncthreads();
    if (h == 0) {
        #pragma unroll
        for (int r = 0; r < 2; ++r) {
            float rs = fast_rcp((redS[r][0] + redS[r][1]) + (redS[r][2] + redS[r][3]));
            weights[(size_t)(b * TQ + gp * 2 + r) * TV + v] = e[r] * rs;
        }
    }
}

__global__ __launch_bounds__(512, 4) void context_kernel_fb(
    const float* __restrict__ weights, const float* __restrict__ value,
    float* __restrict__ ctx) {
    int bid = blockIdx.x;
    int dh = bid & 1;
    int grp = bid >> 1;
    int b = grp >> 6;
    int q0 = (grp & 63) * 4;
    int tid = threadIdx.x;
    int d = tid & 255, vh = tid >> 8;
    __shared__ float w[4][TV];
    __shared__ float part[4][256];
    for (int i = tid; i < 4 * TV; i += 512)
        w[i >> 8][i & 255] = weights[(size_t)(b * TQ + q0 + (i >> 8)) * TV + (i & 255)];
    __syncthreads();
    const float* vb = value + ((size_t)b * TV + vh * 128) * DD + dh * 256 + d;
    const float* wr = &w[0][vh * 128];
    float a0 = 0.f, a1 = 0.f, a2 = 0.f, a3 = 0.f;
    #pragma unroll 8
    for (int t = 0; t < 128; ++t) {
        float vv = vb[(size_t)t * DD];
        a0 = fmaf(wr[0 * TV + t], vv, a0);
        a1 = fmaf(wr[1 * TV + t], vv, a1);
        a2 = fmaf(wr[2 * TV + t], vv, a2);
        a3 = fmaf(wr[3 * TV + t], vv, a3);
    }
    if (vh == 1) {
        part[0][d] = a0; part[1][d] = a1; part[2][d] = a2; part[3][d] = a3;
    }
    __syncthreads();
    if (vh == 0) {
        float* out = ctx + (size_t)(b * TQ + q0) * DD + dh * 256 + d;
        out[0 * DD] = a0 + part[0][d];
        out[1 * DD] = a1 + part[1][d];
        out[2 * DD] = a2 + part[2][d];
        out[3 * DD] = a3 + part[3][d];
    }
}

extern "C" void kernel_launch(void* const* d_in, const int* in_sizes, int n_in,
                              void* d_out, int out_size, void* d_ws, size_t ws_size,
                              hipStream_t stream) {
    const float* query = (const float*)d_in[0];
    const float* value = (const float*)d_in[1];
    const unsigned char* mask = (const unsigned char*)d_in[2];
    const float* W1 = (const float*)d_in[3];
    const float* W2 = (const float*)d_in[4];
    const float* scale = (const float*)d_in[5];

    float* ctx = (float*)d_out;                              // [B,TQ,D]
    float* weights = (float*)d_out + (size_t)BB * TQ * DD;   // [B,TQ,TV]
    float* eqp = (float*)d_ws;                               // 512 KB
    float* ekT = eqp + (size_t)BB * TQ * UU;                 // 512 KB

    int dev = 0, coop = 0;
    hipGetDevice(&dev);                                      // host query, capture-safe
    hipDeviceGetAttribute(&coop, hipDeviceAttributeCooperativeLaunch, dev);

    if (coop) {
        void* args[] = { (void*)&query, (void*)&value, (void*)&mask,
                         (void*)&W1, (void*)&W2, (void*)&scale,
                         (void*)&ctx, (void*)&weights, (void*)&eqp, (void*)&ekT };
        hipLaunchCooperativeKernel((void*)fused_kernel, dim3(512), dim3(512),
                                   args, 0, stream);
    } else {
        proj_kernel<<<512, 512, 0, stream>>>(query, value, W1, W2, eqp, ekT);
        scores_kernel<<<512, 512, 0, stream>>>(eqp, ekT, scale, mask, weights);
        context_kernel_fb<<<512, 512, 0, stream>>>(weights, value, ctx);
    }
}

// Round 9
// 33.086 us; speedup vs baseline: 4.8948x; 4.8948x over previous
//
#include <hip/hip_runtime.h>
#include <math.h>

#define BB 4
#define TQ 256
#define TV 256
#define DD 512
#define UU 128
#define NEGV (-1e9f)

__device__ __forceinline__ float fast_rcp(float x) {
    return __builtin_amdgcn_rcpf(x);   // v_rcp_f32
}

// ---------------- kernel 1: projections -> Eq=exp(2q), Ek=exp(2k) (transposed) ----------------
// 512 blocks x 512 thr. blocks 0..255: q-proj, 256..511: k-proj. 4 rows/block.
// threads = 128 u-cols x 4 K-quarters, combined via LDS. (proven R5 body)
__global__ __launch_bounds__(512, 4) void proj_kernel(
    const float* __restrict__ query, const float* __restrict__ value,
    const float* __restrict__ W1, const float* __restrict__ W2,
    float* __restrict__ eqp /* [B*TQ][U] = exp(2q) */,
    float* __restrict__ ekT /* [B][U][TV] = exp(2k) */) {
    int bid = blockIdx.x;
    int which = bid >> 8;              // 0 = q, 1 = k
    int row0 = (bid & 255) * 4;
    const float* X = which ? value : query;
    const float* W = which ? W2 : W1;

    __shared__ float xs[4 * DD];       // 8 KB: 4 input rows
    __shared__ float cmb[3][4][UU];    // 6 KB: split-K partials
    int tid = threadIdx.x;
    ((float4*)xs)[tid] = ((const float4*)(X + (size_t)row0 * DD))[tid];
    __syncthreads();

    int kc = tid >> 7;                 // K-quarter 0..3
    int u = tid & 127;
    const float* Wp = W + (size_t)(kc * (DD / 4)) * UU + u;
    const float* x0 = xs + kc * (DD / 4);
    float a0 = 0.f, a1 = 0.f, a2 = 0.f, a3 = 0.f;
    #pragma unroll 8
    for (int d = 0; d < DD / 4; ++d) {
        float w = Wp[(size_t)d * UU];          // coalesced across u
        a0 = fmaf(x0[d], w, a0);               // LDS broadcast
        a1 = fmaf(x0[DD + d], w, a1);
        a2 = fmaf(x0[2 * DD + d], w, a2);
        a3 = fmaf(x0[3 * DD + d], w, a3);
    }
    if (kc) {
        cmb[kc - 1][0][u] = a0; cmb[kc - 1][1][u] = a1;
        cmb[kc - 1][2][u] = a2; cmb[kc - 1][3][u] = a3;
    }
    __syncthreads();
    if (!kc) {
        a0 = __expf(2.f * (((a0 + cmb[0][0][u]) + cmb[1][0][u]) + cmb[2][0][u]));
        a1 = __expf(2.f * (((a1 + cmb[0][1][u]) + cmb[1][1][u]) + cmb[2][1][u]));
        a2 = __expf(2.f * (((a2 + cmb[0][2][u]) + cmb[1][2][u]) + cmb[2][2][u]));
        a3 = __expf(2.f * (((a3 + cmb[0][3][u]) + cmb[1][3][u]) + cmb[2][3][u]));
        if (which == 0) {
            float* p = eqp + (size_t)row0 * UU + u;
            p[0 * UU] = a0; p[1 * UU] = a1; p[2 * UU] = a2; p[3 * UU] = a3;
        } else {
            int b = row0 >> 8, v0 = row0 & 255;
            float* p = ekT + ((size_t)b * UU + u) * TV + v0;
            p[0] = a0; p[1] = a1; p[2] = a2; p[3] = a3;
        }
    }
}

// ---------------- kernel 2: scores + masked softmax -> weights ----------------
// 256 blocks x 512 thr; block = 4 q-rows. thread = (vp: float2 v-pair, h: u-quarter).
// Per 8B ek load: 8 rcp + 16 fma -> latency-covered. ekT traffic 32 MB.
// s'[r,v] = -2 * sum_u sc_u * rcp(1 + Eq[r,u]*Ek[u,v])  (softmax shift-invariant)
__global__ __launch_bounds__(512, 4) void scores_kernel(
    const float* __restrict__ eqp, const float* __restrict__ ekT,
    const float* __restrict__ scale, const unsigned char* __restrict__ m,
    float* __restrict__ weights) {
    int blk = blockIdx.x;              // 0..255
    int b = blk >> 6;
    int q0 = (blk & 63) * 4;
    int tid = threadIdx.x;
    int vp = tid & 127;                // float2 v-pair: v = 2vp, 2vp+1
    int h = tid >> 7;                  // u-quarter 0..3 (32 u each)

    __shared__ float eq4[4][UU];       // 2 KB
    __shared__ float sc2[UU];          // 512 B: -2*scale
    __shared__ float pb[3][4][TV];     // 12 KB: partials from h=1..3
    __shared__ float sv[4][TV];        // 4 KB: combined scores
    __shared__ float redM[4][4], redS[4][4];
    __shared__ int flagF, flagB;

    if (tid == 0) { flagF = 0; flagB = 0; }
    eq4[tid >> 7][tid & 127] = eqp[(size_t)(b * TQ + q0) * UU + tid]; // 512 = 4*128
    if (tid < UU) sc2[tid] = -2.f * scale[tid];
    if (tid < 256) {                   // mask layout probe, first 1024 B safe
        uchar4 c4 = ((const uchar4*)m)[tid];
        if (c4.w == 0x3f) flagF = 1;                 // float32 1.0f tail byte
        if (c4.y | c4.z | c4.w) flagB = 1;           // off-word nonzero -> u8
    }
    __syncthreads();

    const float2* kb2 = (const float2*)(ekT + ((size_t)b * UU + h * 32) * TV) + vp;
    float ax0 = 0.f, ax1 = 0.f, ax2 = 0.f, ax3 = 0.f;
    float ay0 = 0.f, ay1 = 0.f, ay2 = 0.f, ay3 = 0.f;
    const float* eqh0 = &eq4[0][h * 32];
    const float* eqh1 = &eq4[1][h * 32];
    const float* eqh2 = &eq4[2][h * 32];
    const float* eqh3 = &eq4[3][h * 32];
    const float* sch = &sc2[h * 32];
    #pragma unroll 8
    for (int i = 0; i < 32; ++i) {
        float2 ek = kb2[(size_t)i * (TV / 2)];       // 8B, coalesced across vp
        float w2 = sch[i];
        float e0 = eqh0[i], e1 = eqh1[i], e2 = eqh2[i], e3 = eqh3[i];
        ax0 = fmaf(w2, fast_rcp(fmaf(e0, ek.x, 1.f)), ax0);
        ay0 = fmaf(w2, fast_rcp(fmaf(e0, ek.y, 1.f)), ay0);
        ax1 = fmaf(w2, fast_rcp(fmaf(e1, ek.x, 1.f)), ax1);
        ay1 = fmaf(w2, fast_rcp(fmaf(e1, ek.y, 1.f)), ay1);
        ax2 = fmaf(w2, fast_rcp(fmaf(e2, ek.x, 1.f)), ax2);
        ay2 = fmaf(w2, fast_rcp(fmaf(e2, ek.y, 1.f)), ay2);
        ax3 = fmaf(w2, fast_rcp(fmaf(e3, ek.x, 1.f)), ax3);
        ay3 = fmaf(w2, fast_rcp(fmaf(e3, ek.y, 1.f)), ay3);
    }
    if (h > 0) {
        pb[h - 1][0][2 * vp] = ax0; pb[h - 1][0][2 * vp + 1] = ay0;
        pb[h - 1][1][2 * vp] = ax1; pb[h - 1][1][2 * vp + 1] = ay1;
        pb[h - 1][2][2 * vp] = ax2; pb[h - 1][2][2 * vp + 1] = ay2;
        pb[h - 1][3][2 * vp] = ax3; pb[h - 1][3][2 * vp + 1] = ay3;
    }
    __syncthreads();
    if (h == 0) {
        sv[0][2 * vp] = ((ax0 + pb[0][0][2 * vp]) + (pb[1][0][2 * vp] + pb[2][0][2 * vp]));
        sv[0][2 * vp + 1] = ((ay0 + pb[0][0][2 * vp + 1]) + (pb[1][0][2 * vp + 1] + pb[2][0][2 * vp + 1]));
        sv[1][2 * vp] = ((ax1 + pb[0][1][2 * vp]) + (pb[1][1][2 * vp] + pb[2][1][2 * vp]));
        sv[1][2 * vp + 1] = ((ay1 + pb[0][1][2 * vp + 1]) + (pb[1][1][2 * vp + 1] + pb[2][1][2 * vp + 1]));
        sv[2][2 * vp] = ((ax2 + pb[0][2][2 * vp]) + (pb[1][2][2 * vp] + pb[2][2][2 * vp]));
        sv[2][2 * vp + 1] = ((ay2 + pb[0][2][2 * vp + 1]) + (pb[1][2][2 * vp + 1] + pb[2][2][2 * vp + 1]));
        sv[3][2 * vp] = ((ax3 + pb[0][3][2 * vp]) + (pb[1][3][2 * vp] + pb[2][3][2 * vp]));
        sv[3][2 * vp + 1] = ((ay3 + pb[0][3][2 * vp + 1]) + (pb[1][3][2 * vp + 1] + pb[2][3][2 * vp + 1]));
    }
    __syncthreads();

    // ---- masked softmax: threads 0..255 own one v each (waves 4-7 redundant) ----
    int v = tid & 255;
    float mk;
    {
        int idx = b * TV + v;
        bool ok;
        if (flagF)      ok = (m[4 * idx + 3] != 0);
        else if (flagB) ok = (m[idx] != 0);
        else            ok = (m[4 * idx] != 0);      // int32 LSB
        mk = ok ? __builtin_inff() : NEGV;
    }
    float s[4], e[4];
    #pragma unroll
    for (int r = 0; r < 4; ++r) s[r] = fminf(sv[r][v], mk);

    int wid = tid >> 6, lane = tid & 63;
    #pragma unroll
    for (int r = 0; r < 4; ++r) {
        float mm = s[r];
        #pragma unroll
        for (int off = 32; off >= 1; off >>= 1) mm = fmaxf(mm, __shfl_xor(mm, off));
        if (tid < 256 && lane == 0) redM[r][wid] = mm;
    }
    __syncthreads();
    #pragma unroll
    for (int r = 0; r < 4; ++r) {
        float mfull = fmaxf(fmaxf(redM[r][0], redM[r][1]),
                            fmaxf(redM[r][2], redM[r][3]));
        e[r] = __expf(s[r] - mfull);
        float t = e[r];
        #pragma unroll
        for (int off = 32; off >= 1; off >>= 1) t += __shfl_xor(t, off);
        if (tid < 256 && lane == 0) redS[r][wid] = t;
    }
    __syncthreads();
    if (tid < 256) {
        #pragma unroll
        for (int r = 0; r < 4; ++r) {
            float rs = fast_rcp((redS[r][0] + redS[r][1]) + (redS[r][2] + redS[r][3]));
            weights[(size_t)(b * TQ + q0 + r) * TV + v] = e[r] * rs;
        }
    }
}

// ---------------- kernel 3: context = weights @ value, in-block 4-way v-split ----------------
// 512 blocks = b(4) x qt(64: 4 rows) x dh(2: 256 d). 512 thr = dp(128 float2) x vh(4: 64 v).
__global__ __launch_bounds__(512, 4) void context_kernel(
    const float* __restrict__ weights, const float* __restrict__ value,
    float* __restrict__ ctx) {
    int bid = blockIdx.x;
    int dh = bid & 1;
    int grp = bid >> 1;                // 0..255
    int b = grp >> 6;
    int q0 = (grp & 63) * 4;
    int tid = threadIdx.x;
    int dp = tid & 127;                // float2 column within 256-d half
    int vh = tid >> 7;                 // v-quarter 0..3 (64 v each)

    __shared__ float w4[4][TV];        // 4 KB
    __shared__ float2 part[3][4][128]; // 12 KB
    for (int i = tid; i < 4 * TV; i += 512)
        w4[i >> 8][i & 255] = weights[(size_t)(b * TQ + q0 + (i >> 8)) * TV + (i & 255)];
    __syncthreads();

    const float2* vb = (const float2*)(value + ((size_t)b * TV + vh * 64) * DD + dh * 256) + dp;
    const float* wr0 = &w4[0][vh * 64];
    const float* wr1 = &w4[1][vh * 64];
    const float* wr2 = &w4[2][vh * 64];
    const float* wr3 = &w4[3][vh * 64];
    float cx0 = 0.f, cx1 = 0.f, cx2 = 0.f, cx3 = 0.f;
    float cy0 = 0.f, cy1 = 0.f, cy2 = 0.f, cy3 = 0.f;
    #pragma unroll 16
    for (int t = 0; t < 64; ++t) {
        float2 vv = vb[(size_t)t * (DD / 2)];        // 8B, coalesced across dp
        float w0 = wr0[t], w1 = wr1[t], w2 = wr2[t], w3 = wr3[t];
        cx0 = fmaf(w0, vv.x, cx0); cy0 = fmaf(w0, vv.y, cy0);
        cx1 = fmaf(w1, vv.x, cx1); cy1 = fmaf(w1, vv.y, cy1);
        cx2 = fmaf(w2, vv.x, cx2); cy2 = fmaf(w2, vv.y, cy2);
        cx3 = fmaf(w3, vv.x, cx3); cy3 = fmaf(w3, vv.y, cy3);
    }
    if (vh > 0) {
        part[vh - 1][0][dp] = make_float2(cx0, cy0);
        part[vh - 1][1][dp] = make_float2(cx1, cy1);
        part[vh - 1][2][dp] = make_float2(cx2, cy2);
        part[vh - 1][3][dp] = make_float2(cx3, cy3);
    }
    __syncthreads();
    if (vh == 0) {
        float2 o0 = make_float2(cx0 + part[0][0][dp].x + part[1][0][dp].x + part[2][0][dp].x,
                                cy0 + part[0][0][dp].y + part[1][0][dp].y + part[2][0][dp].y);
        float2 o1 = make_float2(cx1 + part[0][1][dp].x + part[1][1][dp].x + part[2][1][dp].x,
                                cy1 + part[0][1][dp].y + part[1][1][dp].y + part[2][1][dp].y);
        float2 o2 = make_float2(cx2 + part[0][2][dp].x + part[1][2][dp].x + part[2][2][dp].x,
                                cy2 + part[0][2][dp].y + part[1][2][dp].y + part[2][2][dp].y);
        float2 o3 = make_float2(cx3 + part[0][3][dp].x + part[1][3][dp].x + part[2][3][dp].x,
                                cy3 + part[0][3][dp].y + part[1][3][dp].y + part[2][3][dp].y);
        ((float2*)(ctx + (size_t)(b * TQ + q0 + 0) * DD + dh * 256))[dp] = o0;
        ((float2*)(ctx + (size_t)(b * TQ + q0 + 1) * DD + dh * 256))[dp] = o1;
        ((float2*)(ctx + (size_t)(b * TQ + q0 + 2) * DD + dh * 256))[dp] = o2;
        ((float2*)(ctx + (size_t)(b * TQ + q0 + 3) * DD + dh * 256))[dp] = o3;
    }
}

extern "C" void kernel_launch(void* const* d_in, const int* in_sizes, int n_in,
                              void* d_out, int out_size, void* d_ws, size_t ws_size,
                              hipStream_t stream) {
    const float* query = (const float*)d_in[0];
    const float* value = (const float*)d_in[1];
    const unsigned char* mask = (const unsigned char*)d_in[2];
    const float* W1 = (const float*)d_in[3];
    const float* W2 = (const float*)d_in[4];
    const float* scale = (const float*)d_in[5];

    float* ctx = (float*)d_out;                              // [B,TQ,D]
    float* weights = (float*)d_out + (size_t)BB * TQ * DD;   // [B,TQ,TV]

    float* eqp = (float*)d_ws;                               // 512 KB
    float* ekT = eqp + (size_t)BB * TQ * UU;                 // 512 KB

    proj_kernel<<<512, 512, 0, stream>>>(query, value, W1, W2, eqp, ekT);
    scores_kernel<<<256, 512, 0, stream>>>(eqp, ekT, scale, mask, weights);
    context_kernel<<<512, 512, 0, stream>>>(weights, value, ctx);
}

// Round 10
// 29.929 us; speedup vs baseline: 5.4110x; 1.1055x over previous
//
#include <hip/hip_runtime.h>
#include <math.h>

#define BB 4
#define TQ 256
#define TV 256
#define DD 512
#define UU 128
#define NEGV (-1e9f)

__device__ __forceinline__ float fast_rcp(float x) {
    return __builtin_amdgcn_rcpf(x);   // v_rcp_f32
}

// ---------------- kernel 1: projections -> Eq=exp(2q), Ek=exp(2k) (transposed) ----------------
// (proven R5 body) 512 blocks x 512 thr; 0..255 q-proj, 256..511 k-proj; 4 rows/block.
__global__ __launch_bounds__(512, 4) void proj_kernel(
    const float* __restrict__ query, const float* __restrict__ value,
    const float* __restrict__ W1, const float* __restrict__ W2,
    float* __restrict__ eqp /* [B*TQ][U] = exp(2q) */,
    float* __restrict__ ekT /* [B][U][TV] = exp(2k) */) {
    int bid = blockIdx.x;
    int which = bid >> 8;              // 0 = q, 1 = k
    int row0 = (bid & 255) * 4;
    const float* X = which ? value : query;
    const float* W = which ? W2 : W1;

    __shared__ float xs[4 * DD];       // 8 KB: 4 input rows
    __shared__ float cmb[3][4][UU];    // 6 KB: split-K partials
    int tid = threadIdx.x;
    ((float4*)xs)[tid] = ((const float4*)(X + (size_t)row0 * DD))[tid];
    __syncthreads();

    int kc = tid >> 7;                 // K-quarter 0..3
    int u = tid & 127;
    const float* Wp = W + (size_t)(kc * (DD / 4)) * UU + u;
    const float* x0 = xs + kc * (DD / 4);
    float a0 = 0.f, a1 = 0.f, a2 = 0.f, a3 = 0.f;
    #pragma unroll 8
    for (int d = 0; d < DD / 4; ++d) {
        float w = Wp[(size_t)d * UU];          // coalesced across u
        a0 = fmaf(x0[d], w, a0);               // LDS broadcast
        a1 = fmaf(x0[DD + d], w, a1);
        a2 = fmaf(x0[2 * DD + d], w, a2);
        a3 = fmaf(x0[3 * DD + d], w, a3);
    }
    if (kc) {
        cmb[kc - 1][0][u] = a0; cmb[kc - 1][1][u] = a1;
        cmb[kc - 1][2][u] = a2; cmb[kc - 1][3][u] = a3;
    }
    __syncthreads();
    if (!kc) {
        a0 = __expf(2.f * (((a0 + cmb[0][0][u]) + cmb[1][0][u]) + cmb[2][0][u]));
        a1 = __expf(2.f * (((a1 + cmb[0][1][u]) + cmb[1][1][u]) + cmb[2][1][u]));
        a2 = __expf(2.f * (((a2 + cmb[0][2][u]) + cmb[1][2][u]) + cmb[2][2][u]));
        a3 = __expf(2.f * (((a3 + cmb[0][3][u]) + cmb[1][3][u]) + cmb[2][3][u]));
        if (which == 0) {
            float* p = eqp + (size_t)row0 * UU + u;
            p[0 * UU] = a0; p[1 * UU] = a1; p[2 * UU] = a2; p[3 * UU] = a3;
        } else {
            int b = row0 >> 8, v0 = row0 & 255;
            float* p = ekT + ((size_t)b * UU + u) * TV + v0;
            p[0] = a0; p[1] = a1; p[2] = a2; p[3] = a3;
        }
    }
}

// ---------------- kernel 2: FUSED scores + masked softmax + context ----------------
// 256 blocks x 1024 thr; block = 4 q-rows of one batch (weights row-complete in-block).
// Phase A: s'[r,v] = -2 * sum_u sc_u * rcp(1 + Eq[r,u]*Ek[u,v]) (shift-invariant),
//          u-split-8 across thread groups; masked softmax; weights -> LDS + d_out.
// Phase B: context rows = weights(LDS) @ value, v-split-4 combined in LDS.
__global__ __launch_bounds__(1024, 4) void attn_kernel(
    const float* __restrict__ eqp, const float* __restrict__ ekT,
    const float* __restrict__ scale, const unsigned char* __restrict__ m,
    const float* __restrict__ value,
    float* __restrict__ ctx, float* __restrict__ weights) {
    int blk = blockIdx.x;              // 0..255
    int b = blk >> 6;
    int q0 = (blk & 63) * 4;
    int tid = threadIdx.x;             // 0..1023

    __shared__ float eq4[4][UU];       // 2 KB
    __shared__ float sc2[UU];          // 512 B: -2*scale
    __shared__ union {                 // 28 KB (phases disjoint, sync-separated)
        float pb[7][4][TV];            // phase A: partials from h=1..7
        float2 part[3][4][256];        // phase B: partials from vh=1..3
    } un;
    __shared__ float sv[4][TV];        // 4 KB: scores, then weights
    __shared__ float redM[4][4], redS[4][4];
    __shared__ int flagF, flagB;

    if (tid == 0) { flagF = 0; flagB = 0; }
    if (tid < 512) eq4[tid >> 7][tid & 127] = eqp[(size_t)(b * TQ + q0) * UU + tid];
    else if (tid < 512 + UU) sc2[tid - 512] = -2.f * scale[tid - 512];
    if (tid < 256) {                   // mask layout probe, first 1024 B safe
        uchar4 c4 = ((const uchar4*)m)[tid];
        if (c4.w == 0x3f) flagF = 1;                 // float32 1.0f tail byte
        if (c4.y | c4.z | c4.w) flagB = 1;           // off-word nonzero -> u8
    }
    __syncthreads();

    // ---- phase A: scores, u-split-8 (16 u per group) ----
    {
        int vp = tid & 127;            // float2 v-pair
        int h = tid >> 7;              // u-eighth 0..7
        const float2* kb2 = (const float2*)(ekT + ((size_t)b * UU + h * 16) * TV) + vp;
        const float* eqh0 = &eq4[0][h * 16];
        const float* eqh1 = &eq4[1][h * 16];
        const float* eqh2 = &eq4[2][h * 16];
        const float* eqh3 = &eq4[3][h * 16];
        const float* sch = &sc2[h * 16];
        float ax0 = 0.f, ax1 = 0.f, ax2 = 0.f, ax3 = 0.f;
        float ay0 = 0.f, ay1 = 0.f, ay2 = 0.f, ay3 = 0.f;
        #pragma unroll
        for (int i = 0; i < 16; ++i) {
            float2 ek = kb2[(size_t)i * (TV / 2)];   // 8B, coalesced across vp
            float w2 = sch[i];
            float e0 = eqh0[i], e1 = eqh1[i], e2 = eqh2[i], e3 = eqh3[i];
            ax0 = fmaf(w2, fast_rcp(fmaf(e0, ek.x, 1.f)), ax0);
            ay0 = fmaf(w2, fast_rcp(fmaf(e0, ek.y, 1.f)), ay0);
            ax1 = fmaf(w2, fast_rcp(fmaf(e1, ek.x, 1.f)), ax1);
            ay1 = fmaf(w2, fast_rcp(fmaf(e1, ek.y, 1.f)), ay1);
            ax2 = fmaf(w2, fast_rcp(fmaf(e2, ek.x, 1.f)), ax2);
            ay2 = fmaf(w2, fast_rcp(fmaf(e2, ek.y, 1.f)), ay2);
            ax3 = fmaf(w2, fast_rcp(fmaf(e3, ek.x, 1.f)), ax3);
            ay3 = fmaf(w2, fast_rcp(fmaf(e3, ek.y, 1.f)), ay3);
        }
        if (h > 0) {
            un.pb[h - 1][0][2 * vp] = ax0; un.pb[h - 1][0][2 * vp + 1] = ay0;
            un.pb[h - 1][1][2 * vp] = ax1; un.pb[h - 1][1][2 * vp + 1] = ay1;
            un.pb[h - 1][2][2 * vp] = ax2; un.pb[h - 1][2][2 * vp + 1] = ay2;
            un.pb[h - 1][3][2 * vp] = ax3; un.pb[h - 1][3][2 * vp + 1] = ay3;
        }
        __syncthreads();
        if (h == 0) {
            float rx0 = ax0, ry0 = ay0, rx1 = ax1, ry1 = ay1;
            float rx2 = ax2, ry2 = ay2, rx3 = ax3, ry3 = ay3;
            #pragma unroll
            for (int j = 0; j < 7; ++j) {
                rx0 += un.pb[j][0][2 * vp]; ry0 += un.pb[j][0][2 * vp + 1];
                rx1 += un.pb[j][1][2 * vp]; ry1 += un.pb[j][1][2 * vp + 1];
                rx2 += un.pb[j][2][2 * vp]; ry2 += un.pb[j][2][2 * vp + 1];
                rx3 += un.pb[j][3][2 * vp]; ry3 += un.pb[j][3][2 * vp + 1];
            }
            sv[0][2 * vp] = rx0; sv[0][2 * vp + 1] = ry0;
            sv[1][2 * vp] = rx1; sv[1][2 * vp + 1] = ry1;
            sv[2][2 * vp] = rx2; sv[2][2 * vp + 1] = ry2;
            sv[3][2 * vp] = rx3; sv[3][2 * vp + 1] = ry3;
        }
        __syncthreads();
    }

    // ---- masked softmax: threads 0..255 own one v each ----
    {
        int v = tid & 255;
        float mk;
        {
            int idx = b * TV + v;
            bool ok;
            if (flagF)      ok = (m[4 * idx + 3] != 0);
            else if (flagB) ok = (m[idx] != 0);
            else            ok = (m[4 * idx] != 0);  // int32 LSB
            mk = ok ? __builtin_inff() : NEGV;
        }
        float s[4], e[4];
        #pragma unroll
        for (int r = 0; r < 4; ++r) s[r] = fminf(sv[r][v], mk);

        int wid = tid >> 6, lane = tid & 63;
        #pragma unroll
        for (int r = 0; r < 4; ++r) {
            float mm = s[r];
            #pragma unroll
            for (int off = 32; off >= 1; off >>= 1) mm = fmaxf(mm, __shfl_xor(mm, off));
            if (tid < 256 && lane == 0) redM[r][wid] = mm;
        }
        __syncthreads();
        #pragma unroll
        for (int r = 0; r < 4; ++r) {
            float mfull = fmaxf(fmaxf(redM[r][0], redM[r][1]),
                                fmaxf(redM[r][2], redM[r][3]));
            e[r] = __expf(s[r] - mfull);
            float t = e[r];
            #pragma unroll
            for (int off = 32; off >= 1; off >>= 1) t += __shfl_xor(t, off);
            if (tid < 256 && lane == 0) redS[r][wid] = t;
        }
        __syncthreads();
        if (tid < 256) {
            #pragma unroll
            for (int r = 0; r < 4; ++r) {
                float rs = fast_rcp((redS[r][0] + redS[r][1]) + (redS[r][2] + redS[r][3]));
                float wv = e[r] * rs;
                weights[(size_t)(b * TQ + q0 + r) * TV + v] = wv;
                sv[r][v] = wv;                       // weights for phase B
            }
        }
        __syncthreads();
    }

    // ---- phase B: context = weights(LDS) @ value, v-split-4 ----
    {
        int dp = tid & 255;            // float2 d-column (512 d total)
        int vh = tid >> 8;             // v-quarter 0..3 (64 v each)
        const float2* vb = (const float2*)(value + ((size_t)b * TV + vh * 64) * DD) + dp;
        const float* wr0 = &sv[0][vh * 64];
        const float* wr1 = &sv[1][vh * 64];
        const float* wr2 = &sv[2][vh * 64];
        const float* wr3 = &sv[3][vh * 64];
        float cx0 = 0.f, cx1 = 0.f, cx2 = 0.f, cx3 = 0.f;
        float cy0 = 0.f, cy1 = 0.f, cy2 = 0.f, cy3 = 0.f;
        #pragma unroll 16
        for (int t = 0; t < 64; ++t) {
            float2 vv = vb[(size_t)t * (DD / 2)];    // 8B, coalesced across dp
            float w0 = wr0[t], w1 = wr1[t], w2 = wr2[t], w3 = wr3[t];
            cx0 = fmaf(w0, vv.x, cx0); cy0 = fmaf(w0, vv.y, cy0);
            cx1 = fmaf(w1, vv.x, cx1); cy1 = fmaf(w1, vv.y, cy1);
            cx2 = fmaf(w2, vv.x, cx2); cy2 = fmaf(w2, vv.y, cy2);
            cx3 = fmaf(w3, vv.x, cx3); cy3 = fmaf(w3, vv.y, cy3);
        }
        if (vh > 0) {
            un.part[vh - 1][0][dp] = make_float2(cx0, cy0);
            un.part[vh - 1][1][dp] = make_float2(cx1, cy1);
            un.part[vh - 1][2][dp] = make_float2(cx2, cy2);
            un.part[vh - 1][3][dp] = make_float2(cx3, cy3);
        }
        __syncthreads();
        if (vh == 0) {
            float2 o0 = make_float2(cx0 + un.part[0][0][dp].x + un.part[1][0][dp].x + un.part[2][0][dp].x,
                                    cy0 + un.part[0][0][dp].y + un.part[1][0][dp].y + un.part[2][0][dp].y);
            float2 o1 = make_float2(cx1 + un.part[0][1][dp].x + un.part[1][1][dp].x + un.part[2][1][dp].x,
                                    cy1 + un.part[0][1][dp].y + un.part[1][1][dp].y + un.part[2][1][dp].y);
            float2 o2 = make_float2(cx2 + un.part[0][2][dp].x + un.part[1][2][dp].x + un.part[2][2][dp].x,
                                    cy2 + un.part[0][2][dp].y + un.part[1][2][dp].y + un.part[2][2][dp].y);
            float2 o3 = make_float2(cx3 + un.part[0][3][dp].x + un.part[1][3][dp].x + un.part[2][3][dp].x,
                                    cy3 + un.part[0][3][dp].y + un.part[1][3][dp].y + un.part[2][3][dp].y);
            ((float2*)(ctx + (size_t)(b * TQ + q0 + 0) * DD))[dp] = o0;
            ((float2*)(ctx + (size_t)(b * TQ + q0 + 1) * DD))[dp] = o1;
            ((float2*)(ctx + (size_t)(b * TQ + q0 + 2) * DD))[dp] = o2;
            ((float2*)(ctx + (size_t)(b * TQ + q0 + 3) * DD))[dp] = o3;
        }
    }
}

extern "C" void kernel_launch(void* const* d_in, const int* in_sizes, int n_in,
                              void* d_out, int out_size, void* d_ws, size_t ws_size,
                              hipStream_t stream) {
    const float* query = (const float*)d_in[0];
    const float* value = (const float*)d_in[1];
    const unsigned char* mask = (const unsigned char*)d_in[2];
    const float* W1 = (const float*)d_in[3];
    const float* W2 = (const float*)d_in[4];
    const float* scale = (const float*)d_in[5];

    float* ctx = (float*)d_out;                              // [B,TQ,D]
    float* weights = (float*)d_out + (size_t)BB * TQ * DD;   // [B,TQ,TV]

    float* eqp = (float*)d_ws;                               // 512 KB
    float* ekT = eqp + (size_t)BB * TQ * UU;                 // 512 KB

    proj_kernel<<<512, 512, 0, stream>>>(query, value, W1, W2, eqp, ekT);
    attn_kernel<<<256, 1024, 0, stream>>>(eqp, ekT, scale, mask, value, ctx, weights);
}